// Round 12
// baseline (1167.091 us; speedup 1.0000x reference)
//
#include <hip/hip_runtime.h>
#include <math.h>

typedef unsigned short ushort_t;
typedef unsigned int uint_t;
typedef __attribute__((ext_vector_type(8))) short bf16x8;
typedef __attribute__((ext_vector_type(4))) float f32x4;

#define NTOK 131072          // B*S
#define TM 32                // tokens per block (2 tiles of 16)
#define SROW 584             // A row stride bf16; 1168 B row = 16B-aligned b128 (misalign costs ~330us: R6)
#define K0P 160              // layer0 K padded (132 -> 160)
#define KHP 544              // hidden layers K padded (514 -> 544)
#define EPS 1e-5f
#define THREADS 1024

__device__ __forceinline__ ushort_t f2bf(float f) {
    uint_t x = __float_as_uint(f);
    x += 0x7FFFu + ((x >> 16) & 1u);   // RNE
    return (ushort_t)(x >> 16);
}
__device__ __forceinline__ float bf2f(ushort_t u) {
    return __uint_as_float(((uint_t)u) << 16);
}

// ---- weight prep: W[K][512] fp32 -> Wt[n][k] bf16, zero-padded to Kpad ----
__global__ __launch_bounds__(256) void prep_w(const float* __restrict__ W,
                                              ushort_t* __restrict__ dst,
                                              int K, int Kpad) {
    int n = blockIdx.x;            // 0..511
    for (int k = threadIdx.x; k < Kpad; k += 256) {
        float v = (k < K) ? W[k * 512 + n] : 0.0f;
        dst[n * Kpad + k] = f2bf(v);
    }
}

// One fused layer over TWO 16-token tiles. Waves 0..7 -> tile0, 8..15 -> tile1.
// Per-wave work identical to the proven R3/R11 kernel: 48x64 of C via acc[3][4].
// A rows: tile h base 48h: +0..15 primal, +16..31 u0, +32..47 u1.
template<int KPAD>
__device__ __forceinline__ void do_layer(
    const ushort_t* __restrict__ Wt, const float* __restrict__ bb,
    const float* __restrict__ gg, const float* __restrict__ bev,
    ushort_t* A_s, float (*sbuf)[8][16][6], float (*pbuf)[8])
{
    const int tid  = threadIdx.x;
    const int wv   = tid >> 6;      // wave 0..15
    const int h    = wv >> 3;       // tile 0/1
    const int wc   = wv & 7;        // column-group 0..7
    const int lane = tid & 63;
    const int q    = lane >> 4;     // quad 0..3
    const int c16  = lane & 15;
    const int nb   = wc * 64;       // wave's 64-column base
    const int rbase = 48 * h;       // tile's A row base

    f32x4 acc[3][4];
#pragma unroll
    for (int m = 0; m < 3; m++)
#pragma unroll
        for (int j = 0; j < 4; j++) acc[m][j] = (f32x4){0.f, 0.f, 0.f, 0.f};

    const int koff = q * 8;
    const ushort_t* bp = Wt + (nb + c16) * KPAD + koff;
    const ushort_t* ap = A_s + (rbase + c16) * SROW + koff;

    for (int ks = 0; ks < KPAD / 32; ks++) {
        bf16x8 af[3], bf[4];
#pragma unroll
        for (int m = 0; m < 3; m++)
            af[m] = *(const bf16x8*)(ap + m * 16 * SROW + ks * 32);
#pragma unroll
        for (int j = 0; j < 4; j++)
            bf[j] = *(const bf16x8*)(bp + j * 16 * KPAD + ks * 32);
#pragma unroll
        for (int m = 0; m < 3; m++)
#pragma unroll
            for (int j = 0; j < 4; j++)
                acc[m][j] = __builtin_amdgcn_mfma_f32_16x16x32_bf16(af[m], bf[j], acc[m][j], 0, 0, 0);
    }

    // bias on primal rows
#pragma unroll
    for (int j = 0; j < 4; j++) {
        float bv = bb[nb + 16 * j + c16];
#pragma unroll
        for (int r = 0; r < 4; r++) acc[0][j][r] += bv;
    }

    // wave-local LN stats (6 sums per token over this wave's 64 cols)
    float st[4][6];
#pragma unroll
    for (int r = 0; r < 4; r++) {
        float s1 = 0.f, s2 = 0.f, a0 = 0.f, x0 = 0.f, a1 = 0.f, x1 = 0.f;
#pragma unroll
        for (int j = 0; j < 4; j++) {
            float p = acc[0][j][r], u0 = acc[1][j][r], u1 = acc[2][j][r];
            s1 += p; s2 += p * p;
            a0 += u0; x0 += p * u0;
            a1 += u1; x1 += p * u1;
        }
        st[r][0] = s1; st[r][1] = s2; st[r][2] = a0; st[r][3] = x0; st[r][4] = a1; st[r][5] = x1;
    }
#pragma unroll
    for (int d = 1; d <= 8; d <<= 1)
#pragma unroll
        for (int r = 0; r < 4; r++)
#pragma unroll
            for (int s = 0; s < 6; s++) st[r][s] += __shfl_xor(st[r][s], d);
    if (c16 == 0) {
#pragma unroll
        for (int r = 0; r < 4; r++)
#pragma unroll
            for (int s = 0; s < 6; s++) sbuf[h][wc][4 * q + r][s] = st[r][s];
    }
    __syncthreads();

    // one thread per token (both tiles) finalizes LN params
    if (tid < TM) {
        int th = tid >> 4, tk = tid & 15;
        float s[6] = {0.f, 0.f, 0.f, 0.f, 0.f, 0.f};
#pragma unroll
        for (int ww = 0; ww < 8; ww++)
#pragma unroll
            for (int k = 0; k < 6; k++) s[k] += sbuf[th][ww][tk][k];
        const float inv = 1.0f / 512.0f;
        float mu  = s[0] * inv;
        float var = s[1] * inv - mu * mu;
        float rs  = rsqrtf(var + EPS);
        float dm0 = s[2] * inv, dm1 = s[4] * inv;
        float c0 = rs * (s[3] * inv - mu * dm0);
        float c1 = rs * (s[5] * inv - mu * dm1);
        pbuf[tid][0] = mu; pbuf[tid][1] = rs;
        pbuf[tid][2] = dm0; pbuf[tid][3] = c0;
        pbuf[tid][4] = dm1; pbuf[tid][5] = c1;
    }
    __syncthreads();

    // epilogue: softplus(LN) + JVP, bf16 write-back (own tile only)
    float gv[4], bvv[4];
#pragma unroll
    for (int j = 0; j < 4; j++) {
        gv[j]  = gg[nb + 16 * j + c16];
        bvv[j] = bev[nb + 16 * j + c16];
    }
#pragma unroll
    for (int r = 0; r < 4; r++) {
        int tk = 4 * q + r;                 // token local to tile
        float4 pa = *(const float4*)&pbuf[16 * h + tk][0];
        float4 pb = *(const float4*)&pbuf[16 * h + tk][4];
        float mu = pa.x, rs = pa.y, dm0 = pa.z, c0 = pa.w;
        float dm1 = pb.x, c1 = pb.y;
#pragma unroll
        for (int j = 0; j < 4; j++) {
            int n = nb + 16 * j + c16;
            float p  = acc[0][j][r], u0 = acc[1][j][r], u1 = acc[2][j][r];
            float xh = (p - mu) * rs;
            float y  = fmaf(xh, gv[j], bvv[j]);
            float e  = __expf(-fabsf(y));
            float rinv = 1.0f / (1.0f + e);
            float sig  = (y >= 0.f) ? rinv : e * rinv;
            float sp   = fmaxf(y, 0.f) + __logf(1.0f + e);
            float grs  = gv[j] * rs;
            float dy0  = grs * (u0 - dm0 - xh * c0);
            float dy1  = grs * (u1 - dm1 - xh * c1);
            A_s[(rbase + tk) * SROW + 2 + n]      = f2bf(sp);
            A_s[(rbase + 16 + tk) * SROW + 2 + n] = f2bf(sig * dy0);
            A_s[(rbase + 32 + tk) * SROW + 2 + n] = f2bf(sig * dy1);
        }
    }
    __syncthreads();
}

__global__ __launch_bounds__(THREADS, 4) void ode_mfma(
    const float* __restrict__ t, const float* __restrict__ z, const float* __restrict__ cond,
    const ushort_t* __restrict__ Wt0, const ushort_t* __restrict__ Wt1, const ushort_t* __restrict__ Wt2,
    const float* __restrict__ b0, const float* __restrict__ g0, const float* __restrict__ be0,
    const float* __restrict__ b1, const float* __restrict__ g1, const float* __restrict__ be1,
    const float* __restrict__ b2, const float* __restrict__ g2, const float* __restrict__ be2,
    const float* __restrict__ W3, const float* __restrict__ b3,
    float* __restrict__ out)
{
    __shared__ ushort_t A_s[96 * SROW];       // 112128 B; two tiles of 48 rows
    __shared__ float sbuf[2][8][16][6];       // 6144 B
    __shared__ float pbuf[32][8];             // 1024 B

    const int tid = threadIdx.x;
    const int gm0 = blockIdx.x * TM;          // 32 | gm0 -> all 32 tokens share one batch row

    // ---------------- init A ----------------
    {   uint_t* A32 = (uint_t*)A_s;
        for (int i = tid; i < 96 * SROW / 2; i += THREADS) A32[i] = 0u;
    }
    __syncthreads();
    const float te = t[0];
    if (tid < TM) {
        int tok = tid;                         // 0..31
        int row = 48 * (tok >> 4) + (tok & 15);
        int gm  = gm0 + tok;
        float pos = (float)((gm & 63) + 1) * (1.0f / 64.0f);
        A_s[row * SROW + 0] = f2bf(te);
        A_s[row * SROW + 1] = f2bf(pos);
        A_s[row * SROW + 2] = f2bf(z[gm * 2 + 0]);
        A_s[row * SROW + 3] = f2bf(z[gm * 2 + 1]);
        A_s[(row + 16) * SROW + 2] = 0x3F80;   // u0 = e0 (bf16 1.0)
        A_s[(row + 32) * SROW + 3] = 0x3F80;   // u1 = e1
    }
    {
        int bi = gm0 >> 6;
        for (int i = tid; i < TM * 128; i += THREADS) {
            int tok = i >> 7, c = i & 127;
            int row = 48 * (tok >> 4) + (tok & 15);
            A_s[row * SROW + 4 + c] = f2bf(cond[bi * 128 + c]);
        }
    }
    __syncthreads();

    do_layer<K0P>(Wt0, b0, g0, be0, A_s, sbuf, pbuf);
    do_layer<KHP>(Wt1, b1, g1, be1, A_s, sbuf, pbuf);
    do_layer<KHP>(Wt2, b2, g2, be2, A_s, sbuf, pbuf);

    // ---------------- layer 3: Kin=514 -> 2 outputs + divergence ----------------
    {
        int tok = tid >> 5;       // 0..31
        int l32 = tid & 31;
        int row = 48 * (tok >> 4) + (tok & 15);
        int gm  = gm0 + tok;
        const float2* W3v = (const float2*)W3;
        float a0 = 0.f, a1 = 0.f, d0 = 0.f, d1 = 0.f;
        for (int k = l32; k < 514; k += 32) {
            float2 wv = W3v[k];
            float ax  = bf2f(A_s[row * SROW + k]);
            float au0 = bf2f(A_s[(row + 16) * SROW + k]);
            float au1 = bf2f(A_s[(row + 32) * SROW + k]);
            a0 = fmaf(ax, wv.x, a0);
            a1 = fmaf(ax, wv.y, a1);
            d0 = fmaf(au0, wv.x, d0);
            d1 = fmaf(au1, wv.y, d1);
        }
#pragma unroll
        for (int d = 1; d <= 16; d <<= 1) {
            a0 += __shfl_xor(a0, d); a1 += __shfl_xor(a1, d);
            d0 += __shfl_xor(d0, d); d1 += __shfl_xor(d1, d);
        }
        if (l32 == 0) {
            out[gm * 2 + 0]    = a0 + b3[0];
            out[gm * 2 + 1]    = a1 + b3[1];
            out[NTOK * 2 + gm] = -(d0 + d1);
        }
    }
}

extern "C" void kernel_launch(void* const* d_in, const int* in_sizes, int n_in,
                              void* d_out, int out_size, void* d_ws, size_t ws_size,
                              hipStream_t stream) {
    const float* t    = (const float*)d_in[0];
    const float* z    = (const float*)d_in[1];
    const float* cond = (const float*)d_in[2];
    const float* W0   = (const float*)d_in[3];
    const float* b0   = (const float*)d_in[4];
    const float* g0   = (const float*)d_in[5];
    const float* be0  = (const float*)d_in[6];
    const float* W1   = (const float*)d_in[7];
    const float* b1   = (const float*)d_in[8];
    const float* g1   = (const float*)d_in[9];
    const float* be1  = (const float*)d_in[10];
    const float* W2   = (const float*)d_in[11];
    const float* b2   = (const float*)d_in[12];
    const float* g2   = (const float*)d_in[13];
    const float* be2  = (const float*)d_in[14];
    const float* W3   = (const float*)d_in[15];
    const float* b3   = (const float*)d_in[16];
    float* out = (float*)d_out;

    ushort_t* Wt0 = (ushort_t*)d_ws;                    // 512*160
    ushort_t* Wt1 = Wt0 + 512 * K0P;                    // 512*544
    ushort_t* Wt2 = Wt1 + 512 * KHP;                    // 512*544

    hipLaunchKernelGGL(prep_w, dim3(512), dim3(256), 0, stream, W0, Wt0, 132, K0P);
    hipLaunchKernelGGL(prep_w, dim3(512), dim3(256), 0, stream, W1, Wt1, 514, KHP);
    hipLaunchKernelGGL(prep_w, dim3(512), dim3(256), 0, stream, W2, Wt2, 514, KHP);

    hipLaunchKernelGGL(ode_mfma, dim3(NTOK / TM), dim3(THREADS), 0, stream,
                       t, z, cond, Wt0, Wt1, Wt2,
                       b0, g0, be0, b1, g1, be1, b2, g2, be2, W3, b3, out);
}

// Round 13
// 1028.010 us; speedup vs baseline: 1.1353x; 1.1353x over previous
//
#include <hip/hip_runtime.h>
#include <math.h>

typedef unsigned short ushort_t;
typedef unsigned int uint_t;
typedef __attribute__((ext_vector_type(8))) short bf16x8;
typedef __attribute__((ext_vector_type(4))) float f32x4;

#define NTOK 131072          // B*S
#define TM 16                // tokens per block
#define SROW 584             // A row stride bf16; 1168 B row = 16B-aligned b128 (misalign costs ~330us: R6)
#define K0P 160              // layer0 K padded (132 -> 160)
#define KHP 544              // hidden layers K padded (514 -> 544)
#define EPS 1e-5f

__device__ __forceinline__ ushort_t f2bf(float f) {
    uint_t x = __float_as_uint(f);
    x += 0x7FFFu + ((x >> 16) & 1u);   // RNE
    return (ushort_t)(x >> 16);
}
__device__ __forceinline__ float bf2f(ushort_t u) {
    return __uint_as_float(((uint_t)u) << 16);
}

// ---- weight prep: W[K][512] fp32 -> Wt[n][k] bf16, zero-padded to Kpad ----
__global__ __launch_bounds__(256) void prep_w(const float* __restrict__ W,
                                              ushort_t* __restrict__ dst,
                                              int K, int Kpad) {
    int n = blockIdx.x;            // 0..511
    for (int k = threadIdx.x; k < Kpad; k += 256) {
        float v = (k < K) ? W[k * 512 + n] : 0.0f;
        dst[n * Kpad + k] = f2bf(v);
    }
}

// One fused layer. L0==true: tangent GEMMs are skipped — the L0 tangent
// pre-activations are W0 rows 2,3 (JVP of one-hot through the concat),
// loaded directly from Wfull (fp32). Saves 2/3 of L0 MFMAs + A-reads.
template<int KPAD, bool L0>
__device__ __forceinline__ void do_layer(
    const ushort_t* __restrict__ Wt, const float* __restrict__ Wfull,
    const float* __restrict__ bb,
    const float* __restrict__ gg, const float* __restrict__ bev,
    ushort_t* A_s, float (*sbuf)[16][6], float (*pbuf)[8])
{
    const int tid  = threadIdx.x;
    const int w    = tid >> 6;      // wave 0..7
    const int lane = tid & 63;
    const int q    = lane >> 4;     // quad 0..3
    const int c16  = lane & 15;
    const int nb   = w * 64;        // wave's 64-column base

    constexpr int MT = L0 ? 1 : 3;  // m-tiles in the GEMM

    f32x4 acc[MT][4];
#pragma unroll
    for (int m = 0; m < MT; m++)
#pragma unroll
        for (int j = 0; j < 4; j++) acc[m][j] = (f32x4){0.f, 0.f, 0.f, 0.f};

    const int koff = q * 8;
    const ushort_t* bp = Wt + (nb + c16) * KPAD + koff;
    const ushort_t* ap = A_s + c16 * SROW + koff;

#pragma unroll
    for (int ks = 0; ks < KPAD / 32; ks++) {
        bf16x8 af[MT], bf[4];
#pragma unroll
        for (int m = 0; m < MT; m++)
            af[m] = *(const bf16x8*)(ap + m * 16 * SROW + ks * 32);
#pragma unroll
        for (int j = 0; j < 4; j++)
            bf[j] = *(const bf16x8*)(bp + j * 16 * KPAD + ks * 32);
#pragma unroll
        for (int m = 0; m < MT; m++)
#pragma unroll
            for (int j = 0; j < 4; j++)
                acc[m][j] = __builtin_amdgcn_mfma_f32_16x16x32_bf16(af[m], bf[j], acc[m][j], 0, 0, 0);
    }

    // L0: tangent pre-activations direct from W0 rows 2,3 (token-independent)
    float tu0[4], tu1[4];
    if constexpr (L0) {
#pragma unroll
        for (int j = 0; j < 4; j++) {
            tu0[j] = Wfull[2 * 512 + nb + 16 * j + c16];
            tu1[j] = Wfull[3 * 512 + nb + 16 * j + c16];
        }
    }

    // bias on primal rows
#pragma unroll
    for (int j = 0; j < 4; j++) {
        float bv = bb[nb + 16 * j + c16];
#pragma unroll
        for (int r = 0; r < 4; r++) acc[0][j][r] += bv;
    }

    // wave-local LN stats (6 sums per token over this wave's 64 cols)
    float st[4][6];
#pragma unroll
    for (int r = 0; r < 4; r++) {
        float s1 = 0.f, s2 = 0.f, a0 = 0.f, x0 = 0.f, a1 = 0.f, x1 = 0.f;
#pragma unroll
        for (int j = 0; j < 4; j++) {
            float p  = acc[0][j][r];
            float u0 = L0 ? tu0[j] : acc[1 % MT][j][r];
            float u1 = L0 ? tu1[j] : acc[2 % MT][j][r];
            s1 += p; s2 += p * p;
            a0 += u0; x0 += p * u0;
            a1 += u1; x1 += p * u1;
        }
        st[r][0] = s1; st[r][1] = s2; st[r][2] = a0; st[r][3] = x0; st[r][4] = a1; st[r][5] = x1;
    }
#pragma unroll
    for (int d = 1; d <= 8; d <<= 1)
#pragma unroll
        for (int r = 0; r < 4; r++)
#pragma unroll
            for (int s = 0; s < 6; s++) st[r][s] += __shfl_xor(st[r][s], d);
    if (c16 == 0) {
#pragma unroll
        for (int r = 0; r < 4; r++)
#pragma unroll
            for (int s = 0; s < 6; s++) sbuf[w][4 * q + r][s] = st[r][s];
    }
    __syncthreads();

    // one thread per token finalizes LN params
    if (tid < TM) {
        float s[6] = {0.f, 0.f, 0.f, 0.f, 0.f, 0.f};
#pragma unroll
        for (int ww = 0; ww < 8; ww++)
#pragma unroll
            for (int k = 0; k < 6; k++) s[k] += sbuf[ww][tid][k];
        const float inv = 1.0f / 512.0f;
        float mu  = s[0] * inv;
        float var = s[1] * inv - mu * mu;
        float rs  = rsqrtf(var + EPS);
        float dm0 = s[2] * inv, dm1 = s[4] * inv;
        float c0 = rs * (s[3] * inv - mu * dm0);
        float c1 = rs * (s[5] * inv - mu * dm1);
        pbuf[tid][0] = mu; pbuf[tid][1] = rs;
        pbuf[tid][2] = dm0; pbuf[tid][3] = c0;
        pbuf[tid][4] = dm1; pbuf[tid][5] = c1;
    }
    __syncthreads();

    // epilogue: softplus(LN) + JVP, bf16 write-back
    float gv[4], bvv[4];
#pragma unroll
    for (int j = 0; j < 4; j++) {
        gv[j]  = gg[nb + 16 * j + c16];
        bvv[j] = bev[nb + 16 * j + c16];
    }
#pragma unroll
    for (int r = 0; r < 4; r++) {
        int tok = 4 * q + r;
        float4 pa = *(const float4*)&pbuf[tok][0];
        float4 pb = *(const float4*)&pbuf[tok][4];
        float mu = pa.x, rs = pa.y, dm0 = pa.z, c0 = pa.w;
        float dm1 = pb.x, c1 = pb.y;
#pragma unroll
        for (int j = 0; j < 4; j++) {
            int n = nb + 16 * j + c16;
            float p  = acc[0][j][r];
            float u0 = L0 ? tu0[j] : acc[1 % MT][j][r];
            float u1 = L0 ? tu1[j] : acc[2 % MT][j][r];
            float xh = (p - mu) * rs;
            float y  = fmaf(xh, gv[j], bvv[j]);
            float e  = __expf(-fabsf(y));
            float rinv = 1.0f / (1.0f + e);
            float sig  = (y >= 0.f) ? rinv : e * rinv;
            float sp   = fmaxf(y, 0.f) + __logf(1.0f + e);
            float grs  = gv[j] * rs;
            float dy0  = grs * (u0 - dm0 - xh * c0);
            float dy1  = grs * (u1 - dm1 - xh * c1);
            A_s[tok * SROW + 2 + n]        = f2bf(sp);
            A_s[(16 + tok) * SROW + 2 + n] = f2bf(sig * dy0);
            A_s[(32 + tok) * SROW + 2 + n] = f2bf(sig * dy1);
        }
    }
    __syncthreads();
}

__global__ __launch_bounds__(512, 4) void ode_mfma(
    const float* __restrict__ t, const float* __restrict__ z, const float* __restrict__ cond,
    const ushort_t* __restrict__ Wt0, const ushort_t* __restrict__ Wt1, const ushort_t* __restrict__ Wt2,
    const float* __restrict__ W0full,
    const float* __restrict__ b0, const float* __restrict__ g0, const float* __restrict__ be0,
    const float* __restrict__ b1, const float* __restrict__ g1, const float* __restrict__ be1,
    const float* __restrict__ b2, const float* __restrict__ g2, const float* __restrict__ be2,
    const float* __restrict__ W3, const float* __restrict__ b3,
    float* __restrict__ out)
{
    __shared__ ushort_t A_s[48 * SROW];       // rows 0..15 primal x, 16..31 u0, 32..47 u1
    __shared__ float sbuf[8][16][6];
    __shared__ float pbuf[16][8];

    const int tid = threadIdx.x;

    // ---------------- init A ----------------
    {   uint_t* A32 = (uint_t*)A_s;
        for (int i = tid; i < 48 * SROW / 2; i += 512) A32[i] = 0u;
    }
    __syncthreads();
    const float te = t[0];
    if (tid < TM) {
        int tok = tid;
        int gm  = blockIdx.x * TM + tok;
        int si  = gm & 63;
        float pos = (float)(si + 1) * (1.0f / 64.0f);
        A_s[tok * SROW + 0] = f2bf(te);
        A_s[tok * SROW + 1] = f2bf(pos);
        A_s[tok * SROW + 2] = f2bf(z[gm * 2 + 0]);
        A_s[tok * SROW + 3] = f2bf(z[gm * 2 + 1]);
        // no L0 tangent GEMM -> tangent rows need no one-hot init; their
        // k in [2,514) is written by the L0 epilogue, rest stays zero.
    }
    {   // all 16 tokens of a block share one batch row (16 | 64)
        int bi = (blockIdx.x * TM) >> 6;
        for (int i = tid; i < TM * 128; i += 512) {
            int tok = i >> 7, c = i & 127;
            A_s[tok * SROW + 4 + c] = f2bf(cond[bi * 128 + c]);
        }
    }
    __syncthreads();

    do_layer<K0P, true >(Wt0, W0full, b0, g0, be0, A_s, sbuf, pbuf);
    do_layer<KHP, false>(Wt1, nullptr, b1, g1, be1, A_s, sbuf, pbuf);
    do_layer<KHP, false>(Wt2, nullptr, b2, g2, be2, A_s, sbuf, pbuf);

    // ---------------- layer 3: Kin=514 -> 2 outputs + divergence ----------------
    {
        int tok = tid >> 5;       // 0..15
        int l32 = tid & 31;
        int gm  = blockIdx.x * TM + tok;
        const float2* W3v = (const float2*)W3;
        float a0 = 0.f, a1 = 0.f, d0 = 0.f, d1 = 0.f;
        for (int k = l32; k < 514; k += 32) {
            float2 wv = W3v[k];
            float ax  = bf2f(A_s[tok * SROW + k]);
            float au0 = bf2f(A_s[(16 + tok) * SROW + k]);
            float au1 = bf2f(A_s[(32 + tok) * SROW + k]);
            a0 = fmaf(ax, wv.x, a0);
            a1 = fmaf(ax, wv.y, a1);
            d0 = fmaf(au0, wv.x, d0);
            d1 = fmaf(au1, wv.y, d1);
        }
#pragma unroll
        for (int d = 1; d <= 16; d <<= 1) {
            a0 += __shfl_xor(a0, d); a1 += __shfl_xor(a1, d);
            d0 += __shfl_xor(d0, d); d1 += __shfl_xor(d1, d);
        }
        if (l32 == 0) {
            out[gm * 2 + 0]    = a0 + b3[0];
            out[gm * 2 + 1]    = a1 + b3[1];
            out[NTOK * 2 + gm] = -(d0 + d1);
        }
    }
}

extern "C" void kernel_launch(void* const* d_in, const int* in_sizes, int n_in,
                              void* d_out, int out_size, void* d_ws, size_t ws_size,
                              hipStream_t stream) {
    const float* t    = (const float*)d_in[0];
    const float* z    = (const float*)d_in[1];
    const float* cond = (const float*)d_in[2];
    const float* W0   = (const float*)d_in[3];
    const float* b0   = (const float*)d_in[4];
    const float* g0   = (const float*)d_in[5];
    const float* be0  = (const float*)d_in[6];
    const float* W1   = (const float*)d_in[7];
    const float* b1   = (const float*)d_in[8];
    const float* g1   = (const float*)d_in[9];
    const float* be1  = (const float*)d_in[10];
    const float* W2   = (const float*)d_in[11];
    const float* b2   = (const float*)d_in[12];
    const float* g2   = (const float*)d_in[13];
    const float* be2  = (const float*)d_in[14];
    const float* W3   = (const float*)d_in[15];
    const float* b3   = (const float*)d_in[16];
    float* out = (float*)d_out;

    ushort_t* Wt0 = (ushort_t*)d_ws;                    // 512*160
    ushort_t* Wt1 = Wt0 + 512 * K0P;                    // 512*544
    ushort_t* Wt2 = Wt1 + 512 * KHP;                    // 512*544

    hipLaunchKernelGGL(prep_w, dim3(512), dim3(256), 0, stream, W0, Wt0, 132, K0P);
    hipLaunchKernelGGL(prep_w, dim3(512), dim3(256), 0, stream, W1, Wt1, 514, KHP);
    hipLaunchKernelGGL(prep_w, dim3(512), dim3(256), 0, stream, W2, Wt2, 514, KHP);

    hipLaunchKernelGGL(ode_mfma, dim3(NTOK / TM), dim3(512), 0, stream,
                       t, z, cond, Wt0, Wt1, Wt2, W0,
                       b0, g0, be0, b1, g1, be1, b2, g2, be2, W3, b3, out);
}

// Round 15
// 984.662 us; speedup vs baseline: 1.1853x; 1.0440x over previous
//
#include <hip/hip_runtime.h>
#include <math.h>

typedef unsigned short ushort_t;
typedef unsigned int uint_t;
typedef __attribute__((ext_vector_type(8))) short bf16x8;
typedef __attribute__((ext_vector_type(4))) float f32x4;

#define NTOK 131072          // B*S
#define TM 16                // tokens per block
#define SROW 584             // A row stride bf16; 1168 B row = 16B-aligned b128 (misalign costs ~330us: R6)
#define K0P 160              // layer0 K padded (132 -> 160)
#define KHP 544              // hidden layers K padded (514 -> 544)
#define EPS 1e-5f

__device__ __forceinline__ ushort_t f2bf(float f) {
    uint_t x = __float_as_uint(f);
    x += 0x7FFFu + ((x >> 16) & 1u);   // RNE
    return (ushort_t)(x >> 16);
}
__device__ __forceinline__ float bf2f(ushort_t u) {
    return __uint_as_float(((uint_t)u) << 16);
}

// ---- DPP 16-lane rotation-reduction (VALU pipe; replaces ds_swizzle shuffles) ----
// DPP ctrl must be an IMMEDIATE -> template parameter.
template<int CTRL>
__device__ __forceinline__ float row_ror_add(float v) {
    int r = __builtin_amdgcn_update_dpp(0, __float_as_int(v), CTRL, 0xF, 0xF, true);
    return v + __int_as_float(r);
}
__device__ __forceinline__ float sum16(float v) {
    v = row_ror_add<0x128>(v);   // row_ror:8
    v = row_ror_add<0x124>(v);   // row_ror:4
    v = row_ror_add<0x122>(v);   // row_ror:2
    v = row_ror_add<0x121>(v);   // row_ror:1
    return v;                    // all 16 lanes of the row hold the total
}

// ---- weight prep: W[K][512] fp32 -> Wt[n][k] bf16, zero-padded to Kpad ----
__global__ __launch_bounds__(256) void prep_w(const float* __restrict__ W,
                                              ushort_t* __restrict__ dst,
                                              int K, int Kpad) {
    int n = blockIdx.x;            // 0..511
    for (int k = threadIdx.x; k < Kpad; k += 256) {
        float v = (k < K) ? W[k * 512 + n] : 0.0f;
        dst[n * Kpad + k] = f2bf(v);
    }
}

// One fused layer. L0==true: tangent GEMMs skipped — L0 tangent pre-activations
// are W0 rows 2,3 (JVP of one-hot through the concat), loaded directly.
template<int KPAD, bool L0>
__device__ __forceinline__ void do_layer(
    const ushort_t* __restrict__ Wt, const float* __restrict__ Wfull,
    const float* __restrict__ bb,
    const float* __restrict__ gg, const float* __restrict__ bev,
    ushort_t* A_s, float (*sbuf)[16][6], float (*pbuf)[8])
{
    const int tid  = threadIdx.x;
    const int w    = tid >> 6;      // wave 0..7
    const int lane = tid & 63;
    const int q    = lane >> 4;     // quad 0..3
    const int c16  = lane & 15;
    const int nb   = w * 64;        // wave's 64-column base

    constexpr int MT = L0 ? 1 : 3;  // m-tiles in the GEMM

    f32x4 acc[MT][4];
#pragma unroll
    for (int m = 0; m < MT; m++)
#pragma unroll
        for (int j = 0; j < 4; j++) acc[m][j] = (f32x4){0.f, 0.f, 0.f, 0.f};

    const int koff = q * 8;
    const ushort_t* bp = Wt + (nb + c16) * KPAD + koff;
    const ushort_t* ap = A_s + c16 * SROW + koff;

#pragma unroll
    for (int ks = 0; ks < KPAD / 32; ks++) {
        bf16x8 af[MT], bf[4];
#pragma unroll
        for (int m = 0; m < MT; m++)
            af[m] = *(const bf16x8*)(ap + m * 16 * SROW + ks * 32);
#pragma unroll
        for (int j = 0; j < 4; j++)
            bf[j] = *(const bf16x8*)(bp + j * 16 * KPAD + ks * 32);
#pragma unroll
        for (int m = 0; m < MT; m++)
#pragma unroll
            for (int j = 0; j < 4; j++)
                acc[m][j] = __builtin_amdgcn_mfma_f32_16x16x32_bf16(af[m], bf[j], acc[m][j], 0, 0, 0);
    }

    // L0: tangent pre-activations direct from W0 rows 2,3 (token-independent)
    float tu0[4], tu1[4];
    if constexpr (L0) {
#pragma unroll
        for (int j = 0; j < 4; j++) {
            tu0[j] = Wfull[2 * 512 + nb + 16 * j + c16];
            tu1[j] = Wfull[3 * 512 + nb + 16 * j + c16];
        }
    }

    // bias on primal rows
#pragma unroll
    for (int j = 0; j < 4; j++) {
        float bv = bb[nb + 16 * j + c16];
#pragma unroll
        for (int r = 0; r < 4; r++) acc[0][j][r] += bv;
    }

    // wave-local LN stats (6 sums per token over this wave's 64 cols) — DPP reduction
    float st[4][6];
#pragma unroll
    for (int r = 0; r < 4; r++) {
        float s1 = 0.f, s2 = 0.f, a0 = 0.f, x0 = 0.f, a1 = 0.f, x1 = 0.f;
#pragma unroll
        for (int j = 0; j < 4; j++) {
            float p  = acc[0][j][r];
            float u0 = L0 ? tu0[j] : acc[1 % MT][j][r];
            float u1 = L0 ? tu1[j] : acc[2 % MT][j][r];
            s1 += p; s2 += p * p;
            a0 += u0; x0 += p * u0;
            a1 += u1; x1 += p * u1;
        }
        st[r][0] = s1; st[r][1] = s2; st[r][2] = a0; st[r][3] = x0; st[r][4] = a1; st[r][5] = x1;
    }
#pragma unroll
    for (int r = 0; r < 4; r++)
#pragma unroll
        for (int s = 0; s < 6; s++) st[r][s] = sum16(st[r][s]);
    if (c16 == 0) {
#pragma unroll
        for (int r = 0; r < 4; r++)
#pragma unroll
            for (int s = 0; s < 6; s++) sbuf[w][4 * q + r][s] = st[r][s];
    }
    __syncthreads();

    // one thread per token finalizes LN params
    if (tid < TM) {
        float s[6] = {0.f, 0.f, 0.f, 0.f, 0.f, 0.f};
#pragma unroll
        for (int ww = 0; ww < 8; ww++)
#pragma unroll
            for (int k = 0; k < 6; k++) s[k] += sbuf[ww][tid][k];
        const float inv = 1.0f / 512.0f;
        float mu  = s[0] * inv;
        float var = s[1] * inv - mu * mu;
        float rs  = rsqrtf(var + EPS);
        float dm0 = s[2] * inv, dm1 = s[4] * inv;
        float c0 = rs * (s[3] * inv - mu * dm0);
        float c1 = rs * (s[5] * inv - mu * dm1);
        pbuf[tid][0] = mu; pbuf[tid][1] = rs;
        pbuf[tid][2] = dm0; pbuf[tid][3] = c0;
        pbuf[tid][4] = dm1; pbuf[tid][5] = c1;
    }
    __syncthreads();

    // epilogue: softplus(LN) + JVP, bf16 write-back
    float gv[4], bvv[4];
#pragma unroll
    for (int j = 0; j < 4; j++) {
        gv[j]  = gg[nb + 16 * j + c16];
        bvv[j] = bev[nb + 16 * j + c16];
    }
#pragma unroll
    for (int r = 0; r < 4; r++) {
        int tok = 4 * q + r;
        float4 pa = *(const float4*)&pbuf[tok][0];
        float4 pb = *(const float4*)&pbuf[tok][4];
        float mu = pa.x, rs = pa.y, dm0 = pa.z, c0 = pa.w;
        float dm1 = pb.x, c1 = pb.y;
#pragma unroll
        for (int j = 0; j < 4; j++) {
            int n = nb + 16 * j + c16;
            float p  = acc[0][j][r];
            float u0 = L0 ? tu0[j] : acc[1 % MT][j][r];
            float u1 = L0 ? tu1[j] : acc[2 % MT][j][r];
            float xh = (p - mu) * rs;
            float y  = fmaf(xh, gv[j], bvv[j]);
            float e  = __expf(-fabsf(y));
            float rinv = 1.0f / (1.0f + e);
            float sig  = (y >= 0.f) ? rinv : e * rinv;
            float sp   = fmaxf(y, 0.f) + __logf(1.0f + e);
            float grs  = gv[j] * rs;
            float dy0  = grs * (u0 - dm0 - xh * c0);
            float dy1  = grs * (u1 - dm1 - xh * c1);
            A_s[tok * SROW + 2 + n]        = f2bf(sp);
            A_s[(16 + tok) * SROW + 2 + n] = f2bf(sig * dy0);
            A_s[(32 + tok) * SROW + 2 + n] = f2bf(sig * dy1);
        }
    }
    __syncthreads();
}

__global__ __launch_bounds__(512, 4) void ode_mfma(
    const float* __restrict__ t, const float* __restrict__ z, const float* __restrict__ cond,
    const ushort_t* __restrict__ Wt0, const ushort_t* __restrict__ Wt1, const ushort_t* __restrict__ Wt2,
    const float* __restrict__ W0full,
    const float* __restrict__ b0, const float* __restrict__ g0, const float* __restrict__ be0,
    const float* __restrict__ b1, const float* __restrict__ g1, const float* __restrict__ be1,
    const float* __restrict__ b2, const float* __restrict__ g2, const float* __restrict__ be2,
    const float* __restrict__ W3, const float* __restrict__ b3,
    float* __restrict__ out)
{
    __shared__ ushort_t A_s[48 * SROW];       // rows 0..15 primal x, 16..31 u0, 32..47 u1
    __shared__ float sbuf[8][16][6];
    __shared__ float pbuf[16][8];

    const int tid = threadIdx.x;

    // ---------------- init A ----------------
    {   uint_t* A32 = (uint_t*)A_s;
        for (int i = tid; i < 48 * SROW / 2; i += 512) A32[i] = 0u;
    }
    __syncthreads();
    const float te = t[0];
    if (tid < TM) {
        int tok = tid;
        int gm  = blockIdx.x * TM + tok;
        int si  = gm & 63;
        float pos = (float)(si + 1) * (1.0f / 64.0f);
        A_s[tok * SROW + 0] = f2bf(te);
        A_s[tok * SROW + 1] = f2bf(pos);
        A_s[tok * SROW + 2] = f2bf(z[gm * 2 + 0]);
        A_s[tok * SROW + 3] = f2bf(z[gm * 2 + 1]);
        // L0 tangent GEMM is skipped; tangent rows' k in [2,514) written by L0 epilogue.
    }
    {   // all 16 tokens of a block share one batch row (16 | 64)
        int bi = (blockIdx.x * TM) >> 6;
        for (int i = tid; i < TM * 128; i += 512) {
            int tok = i >> 7, c = i & 127;
            A_s[tok * SROW + 4 + c] = f2bf(cond[bi * 128 + c]);
        }
    }
    __syncthreads();

    do_layer<K0P, true >(Wt0, W0full, b0, g0, be0, A_s, sbuf, pbuf);
    do_layer<KHP, false>(Wt1, nullptr, b1, g1, be1, A_s, sbuf, pbuf);
    do_layer<KHP, false>(Wt2, nullptr, b2, g2, be2, A_s, sbuf, pbuf);

    // ---------------- layer 3: Kin=514 -> 2 outputs + divergence ----------------
    {
        int tok = tid >> 5;       // 0..15
        int l32 = tid & 31;
        int gm  = blockIdx.x * TM + tok;
        const float2* W3v = (const float2*)W3;
        float a0 = 0.f, a1 = 0.f, d0 = 0.f, d1 = 0.f;
        for (int k = l32; k < 514; k += 32) {
            float2 wv = W3v[k];
            float ax  = bf2f(A_s[tok * SROW + k]);
            float au0 = bf2f(A_s[(16 + tok) * SROW + k]);
            float au1 = bf2f(A_s[(32 + tok) * SROW + k]);
            a0 = fmaf(ax, wv.x, a0);
            a1 = fmaf(ax, wv.y, a1);
            d0 = fmaf(au0, wv.x, d0);
            d1 = fmaf(au1, wv.y, d1);
        }
#pragma unroll
        for (int d = 1; d <= 16; d <<= 1) {
            a0 += __shfl_xor(a0, d); a1 += __shfl_xor(a1, d);
            d0 += __shfl_xor(d0, d); d1 += __shfl_xor(d1, d);
        }
        if (l32 == 0) {
            out[gm * 2 + 0]    = a0 + b3[0];
            out[gm * 2 + 1]    = a1 + b3[1];
            out[NTOK * 2 + gm] = -(d0 + d1);
        }
    }
}

extern "C" void kernel_launch(void* const* d_in, const int* in_sizes, int n_in,
                              void* d_out, int out_size, void* d_ws, size_t ws_size,
                              hipStream_t stream) {
    const float* t    = (const float*)d_in[0];
    const float* z    = (const float*)d_in[1];
    const float* cond = (const float*)d_in[2];
    const float* W0   = (const float*)d_in[3];
    const float* b0   = (const float*)d_in[4];
    const float* g0   = (const float*)d_in[5];
    const float* be0  = (const float*)d_in[6];
    const float* W1   = (const float*)d_in[7];
    const float* b1   = (const float*)d_in[8];
    const float* g1   = (const float*)d_in[9];
    const float* be1  = (const float*)d_in[10];
    const float* W2   = (const float*)d_in[11];
    const float* b2   = (const float*)d_in[12];
    const float* g2   = (const float*)d_in[13];
    const float* be2  = (const float*)d_in[14];
    const float* W3   = (const float*)d_in[15];
    const float* b3   = (const float*)d_in[16];
    float* out = (float*)d_out;

    ushort_t* Wt0 = (ushort_t*)d_ws;                    // 512*160
    ushort_t* Wt1 = Wt0 + 512 * K0P;                    // 512*544
    ushort_t* Wt2 = Wt1 + 512 * KHP;                    // 512*544

    hipLaunchKernelGGL(prep_w, dim3(512), dim3(256), 0, stream, W0, Wt0, 132, K0P);
    hipLaunchKernelGGL(prep_w, dim3(512), dim3(256), 0, stream, W1, Wt1, 514, KHP);
    hipLaunchKernelGGL(prep_w, dim3(512), dim3(256), 0, stream, W2, Wt2, 514, KHP);

    hipLaunchKernelGGL(ode_mfma, dim3(NTOK / TM), dim3(512), 0, stream,
                       t, z, cond, Wt0, Wt1, Wt2, W0,
                       b0, g0, be0, b1, g1, be1, b2, g2, be2, W3, b3, out);
}

// Round 18
// 981.443 us; speedup vs baseline: 1.1892x; 1.0033x over previous
//
#include <hip/hip_runtime.h>
#include <math.h>

typedef unsigned short ushort_t;
typedef unsigned int uint_t;
typedef __attribute__((ext_vector_type(8))) short bf16x8;
typedef __attribute__((ext_vector_type(4))) float f32x4;

#define NTOK 131072          // B*S
#define TM 16                // tokens per block
#define SROW 584             // A row stride bf16; 1168 B row = 16B-aligned b128 (misalign costs ~330us: R6)
#define K0P 160              // layer0 K padded (132 -> 160)
#define KHP 544              // hidden layers K padded (514 -> 544)
#define EPS 1e-5f

__device__ __forceinline__ ushort_t f2bf(float f) {
    uint_t x = __float_as_uint(f);
    x += 0x7FFFu + ((x >> 16) & 1u);   // RNE
    return (ushort_t)(x >> 16);
}
__device__ __forceinline__ float bf2f(ushort_t u) {
    return __uint_as_float(((uint_t)u) << 16);
}

// ---- DPP 16-lane rotation-reduction (VALU pipe; replaces ds_swizzle shuffles) ----
// DPP ctrl must be an IMMEDIATE -> template parameter.
template<int CTRL>
__device__ __forceinline__ float row_ror_add(float v) {
    int r = __builtin_amdgcn_update_dpp(0, __float_as_int(v), CTRL, 0xF, 0xF, true);
    return v + __int_as_float(r);
}
__device__ __forceinline__ float sum16(float v) {
    v = row_ror_add<0x128>(v);   // row_ror:8
    v = row_ror_add<0x124>(v);   // row_ror:4
    v = row_ror_add<0x122>(v);   // row_ror:2
    v = row_ror_add<0x121>(v);   // row_ror:1
    return v;                    // all 16 lanes of the row hold the total
}

// ---- weight prep: W[K][512] fp32 -> Wt[n][k] bf16, zero-padded to Kpad ----
__global__ __launch_bounds__(256) void prep_w(const float* __restrict__ W,
                                              ushort_t* __restrict__ dst,
                                              int K, int Kpad) {
    int n = blockIdx.x;            // 0..511
    for (int k = threadIdx.x; k < Kpad; k += 256) {
        float v = (k < K) ? W[k * 512 + n] : 0.0f;
        dst[n * Kpad + k] = f2bf(v);
    }
}

// One fused layer. L0==true: tangent GEMMs skipped — L0 tangent pre-activations
// are W0 rows 2,3 (JVP of one-hot through the concat), loaded directly.
template<int KPAD, bool L0>
__device__ __forceinline__ void do_layer(
    const ushort_t* __restrict__ Wt, const float* __restrict__ Wfull,
    const float* __restrict__ bb,
    const float* __restrict__ gg, const float* __restrict__ bev,
    ushort_t* A_s, float (*sbuf)[16][6], float (*pbuf)[8])
{
    const int tid  = threadIdx.x;
    const int w    = tid >> 6;      // wave 0..7
    const int lane = tid & 63;
    const int q    = lane >> 4;     // quad 0..3
    const int c16  = lane & 15;
    const int nb   = w * 64;        // wave's 64-column base

    constexpr int MT = L0 ? 1 : 3;  // m-tiles in the GEMM

    f32x4 acc[MT][4];
#pragma unroll
    for (int m = 0; m < MT; m++)
#pragma unroll
        for (int j = 0; j < 4; j++) acc[m][j] = (f32x4){0.f, 0.f, 0.f, 0.f};

    const int koff = q * 8;
    const ushort_t* bp = Wt + (nb + c16) * KPAD + koff;
    const ushort_t* ap = A_s + c16 * SROW + koff;

#pragma unroll
    for (int ks = 0; ks < KPAD / 32; ks++) {
        bf16x8 af[MT], bf[4];
#pragma unroll
        for (int m = 0; m < MT; m++)
            af[m] = *(const bf16x8*)(ap + m * 16 * SROW + ks * 32);
#pragma unroll
        for (int j = 0; j < 4; j++)
            bf[j] = *(const bf16x8*)(bp + j * 16 * KPAD + ks * 32);
#pragma unroll
        for (int m = 0; m < MT; m++)
#pragma unroll
            for (int j = 0; j < 4; j++)
                acc[m][j] = __builtin_amdgcn_mfma_f32_16x16x32_bf16(af[m], bf[j], acc[m][j], 0, 0, 0);
    }

    // L0: tangent pre-activations direct from W0 rows 2,3 (token-independent)
    float tu0[4], tu1[4];
    if constexpr (L0) {
#pragma unroll
        for (int j = 0; j < 4; j++) {
            tu0[j] = Wfull[2 * 512 + nb + 16 * j + c16];
            tu1[j] = Wfull[3 * 512 + nb + 16 * j + c16];
        }
    }

    // bias on primal rows
#pragma unroll
    for (int j = 0; j < 4; j++) {
        float bv = bb[nb + 16 * j + c16];
#pragma unroll
        for (int r = 0; r < 4; r++) acc[0][j][r] += bv;
    }

    // wave-local LN stats (6 sums per token over this wave's 64 cols) — DPP reduction
    float st[4][6];
#pragma unroll
    for (int r = 0; r < 4; r++) {
        float s1 = 0.f, s2 = 0.f, a0 = 0.f, x0 = 0.f, a1 = 0.f, x1 = 0.f;
#pragma unroll
        for (int j = 0; j < 4; j++) {
            float p  = acc[0][j][r];
            float u0 = L0 ? tu0[j] : acc[1 % MT][j][r];
            float u1 = L0 ? tu1[j] : acc[2 % MT][j][r];
            s1 += p; s2 += p * p;
            a0 += u0; x0 += p * u0;
            a1 += u1; x1 += p * u1;
        }
        st[r][0] = s1; st[r][1] = s2; st[r][2] = a0; st[r][3] = x0; st[r][4] = a1; st[r][5] = x1;
    }
#pragma unroll
    for (int r = 0; r < 4; r++)
#pragma unroll
        for (int s = 0; s < 6; s++) st[r][s] = sum16(st[r][s]);
    if (c16 == 0) {
#pragma unroll
        for (int r = 0; r < 4; r++)
#pragma unroll
            for (int s = 0; s < 6; s++) sbuf[w][4 * q + r][s] = st[r][s];
    }
    __syncthreads();

    // one thread per token finalizes LN params
    if (tid < TM) {
        float s[6] = {0.f, 0.f, 0.f, 0.f, 0.f, 0.f};
#pragma unroll
        for (int ww = 0; ww < 8; ww++)
#pragma unroll
            for (int k = 0; k < 6; k++) s[k] += sbuf[ww][tid][k];
        const float inv = 1.0f / 512.0f;
        float mu  = s[0] * inv;
        float var = s[1] * inv - mu * mu;
        float rs  = rsqrtf(var + EPS);
        float dm0 = s[2] * inv, dm1 = s[4] * inv;
        float c0 = rs * (s[3] * inv - mu * dm0);
        float c1 = rs * (s[5] * inv - mu * dm1);
        pbuf[tid][0] = mu; pbuf[tid][1] = rs;
        pbuf[tid][2] = dm0; pbuf[tid][3] = c0;
        pbuf[tid][4] = dm1; pbuf[tid][5] = c1;
    }
    __syncthreads();

    // epilogue: softplus(LN) + JVP, bf16 write-back
    float gv[4], bvv[4];
#pragma unroll
    for (int j = 0; j < 4; j++) {
        gv[j]  = gg[nb + 16 * j + c16];
        bvv[j] = bev[nb + 16 * j + c16];
    }
#pragma unroll
    for (int r = 0; r < 4; r++) {
        int tok = 4 * q + r;
        float4 pa = *(const float4*)&pbuf[tok][0];
        float4 pb = *(const float4*)&pbuf[tok][4];
        float mu = pa.x, rs = pa.y, dm0 = pa.z, c0 = pa.w;
        float dm1 = pb.x, c1 = pb.y;
#pragma unroll
        for (int j = 0; j < 4; j++) {
            int n = nb + 16 * j + c16;
            float p  = acc[0][j][r];
            float u0 = L0 ? tu0[j] : acc[1 % MT][j][r];
            float u1 = L0 ? tu1[j] : acc[2 % MT][j][r];
            float xh = (p - mu) * rs;
            float y  = fmaf(xh, gv[j], bvv[j]);
            float e  = __expf(-fabsf(y));
            float rinv = 1.0f / (1.0f + e);
            float sig  = (y >= 0.f) ? rinv : e * rinv;
            float sp   = fmaxf(y, 0.f) + __logf(1.0f + e);
            float grs  = gv[j] * rs;
            float dy0  = grs * (u0 - dm0 - xh * c0);
            float dy1  = grs * (u1 - dm1 - xh * c1);
            A_s[tok * SROW + 2 + n]        = f2bf(sp);
            A_s[(16 + tok) * SROW + 2 + n] = f2bf(sig * dy0);
            A_s[(32 + tok) * SROW + 2 + n] = f2bf(sig * dy1);
        }
    }
    __syncthreads();
}

__global__ __launch_bounds__(512, 4) void ode_mfma(
    const float* __restrict__ t, const float* __restrict__ z, const float* __restrict__ cond,
    const ushort_t* __restrict__ Wt0, const ushort_t* __restrict__ Wt1, const ushort_t* __restrict__ Wt2,
    const float* __restrict__ W0full,
    const float* __restrict__ b0, const float* __restrict__ g0, const float* __restrict__ be0,
    const float* __restrict__ b1, const float* __restrict__ g1, const float* __restrict__ be1,
    const float* __restrict__ b2, const float* __restrict__ g2, const float* __restrict__ be2,
    const float* __restrict__ W3, const float* __restrict__ b3,
    float* __restrict__ out)
{
    __shared__ ushort_t A_s[48 * SROW];       // rows 0..15 primal x, 16..31 u0, 32..47 u1
    __shared__ float sbuf[8][16][6];
    __shared__ float pbuf[16][8];

    const int tid = threadIdx.x;

    // ---------------- init A ----------------
    {   uint_t* A32 = (uint_t*)A_s;
        for (int i = tid; i < 48 * SROW / 2; i += 512) A32[i] = 0u;
    }
    __syncthreads();
    const float te = t[0];
    if (tid < TM) {
        int tok = tid;
        int gm  = blockIdx.x * TM + tok;
        int si  = gm & 63;
        float pos = (float)(si + 1) * (1.0f / 64.0f);
        A_s[tok * SROW + 0] = f2bf(te);
        A_s[tok * SROW + 1] = f2bf(pos);
        A_s[tok * SROW + 2] = f2bf(z[gm * 2 + 0]);
        A_s[tok * SROW + 3] = f2bf(z[gm * 2 + 1]);
        // L0 tangent GEMM is skipped; tangent rows' k in [2,514) written by L0 epilogue.
    }
    {   // all 16 tokens of a block share one batch row (16 | 64)
        int bi = (blockIdx.x * TM) >> 6;
        for (int i = tid; i < TM * 128; i += 512) {
            int tok = i >> 7, c = i & 127;
            A_s[tok * SROW + 4 + c] = f2bf(cond[bi * 128 + c]);
        }
    }
    __syncthreads();

    do_layer<K0P, true >(Wt0, W0full, b0, g0, be0, A_s, sbuf, pbuf);
    do_layer<KHP, false>(Wt1, nullptr, b1, g1, be1, A_s, sbuf, pbuf);
    do_layer<KHP, false>(Wt2, nullptr, b2, g2, be2, A_s, sbuf, pbuf);

    // ---------------- layer 3: Kin=514 -> 2 outputs + divergence ----------------
    {
        int tok = tid >> 5;       // 0..15
        int l32 = tid & 31;
        int gm  = blockIdx.x * TM + tok;
        const float2* W3v = (const float2*)W3;
        float a0 = 0.f, a1 = 0.f, d0 = 0.f, d1 = 0.f;
        for (int k = l32; k < 514; k += 32) {
            float2 wv = W3v[k];
            float ax  = bf2f(A_s[tok * SROW + k]);
            float au0 = bf2f(A_s[(16 + tok) * SROW + k]);
            float au1 = bf2f(A_s[(32 + tok) * SROW + k]);
            a0 = fmaf(ax, wv.x, a0);
            a1 = fmaf(ax, wv.y, a1);
            d0 = fmaf(au0, wv.x, d0);
            d1 = fmaf(au1, wv.y, d1);
        }
#pragma unroll
        for (int d = 1; d <= 16; d <<= 1) {
            a0 += __shfl_xor(a0, d); a1 += __shfl_xor(a1, d);
            d0 += __shfl_xor(d0, d); d1 += __shfl_xor(d1, d);
        }
        if (l32 == 0) {
            out[gm * 2 + 0]    = a0 + b3[0];
            out[gm * 2 + 1]    = a1 + b3[1];
            out[NTOK * 2 + gm] = -(d0 + d1);
        }
    }
}

extern "C" void kernel_launch(void* const* d_in, const int* in_sizes, int n_in,
                              void* d_out, int out_size, void* d_ws, size_t ws_size,
                              hipStream_t stream) {
    const float* t    = (const float*)d_in[0];
    const float* z    = (const float*)d_in[1];
    const float* cond = (const float*)d_in[2];
    const float* W0   = (const float*)d_in[3];
    const float* b0   = (const float*)d_in[4];
    const float* g0   = (const float*)d_in[5];
    const float* be0  = (const float*)d_in[6];
    const float* W1   = (const float*)d_in[7];
    const float* b1   = (const float*)d_in[8];
    const float* g1   = (const float*)d_in[9];
    const float* be1  = (const float*)d_in[10];
    const float* W2   = (const float*)d_in[11];
    const float* b2   = (const float*)d_in[12];
    const float* g2   = (const float*)d_in[13];
    const float* be2  = (const float*)d_in[14];
    const float* W3   = (const float*)d_in[15];
    const float* b3   = (const float*)d_in[16];
    float* out = (float*)d_out;

    ushort_t* Wt0 = (ushort_t*)d_ws;                    // 512*160
    ushort_t* Wt1 = Wt0 + 512 * K0P;                    // 512*544
    ushort_t* Wt2 = Wt1 + 512 * KHP;                    // 512*544

    hipLaunchKernelGGL(prep_w, dim3(512), dim3(256), 0, stream, W0, Wt0, 132, K0P);
    hipLaunchKernelGGL(prep_w, dim3(512), dim3(256), 0, stream, W1, Wt1, 514, KHP);
    hipLaunchKernelGGL(prep_w, dim3(512), dim3(256), 0, stream, W2, Wt2, 514, KHP);

    hipLaunchKernelGGL(ode_mfma, dim3(NTOK / TM), dim3(512), 0, stream,
                       t, z, cond, Wt0, Wt1, Wt2, W0,
                       b0, g0, be0, b1, g1, be1, b2, g2, be2, W3, b3, out);
}

// Round 19
// 973.110 us; speedup vs baseline: 1.1993x; 1.0086x over previous
//
#include <hip/hip_runtime.h>
#include <math.h>

typedef unsigned short ushort_t;
typedef unsigned int uint_t;
typedef __attribute__((ext_vector_type(8))) short bf16x8;
typedef __attribute__((ext_vector_type(4))) float f32x4;

#define NTOK 131072          // B*S
#define TM 16                // tokens per block
#define SROW 584             // A row stride bf16; 1168 B row = 16B-aligned b128 (misalign costs ~330us: R6)
#define K0P 160              // layer0 K padded (132 -> 160)
#define KHP 544              // hidden layers K padded (514 -> 544)
#define EPS 1e-5f

__device__ __forceinline__ ushort_t f2bf(float f) {
    uint_t x = __float_as_uint(f);
    x += 0x7FFFu + ((x >> 16) & 1u);   // RNE
    return (ushort_t)(x >> 16);
}
__device__ __forceinline__ float bf2f(ushort_t u) {
    return __uint_as_float(((uint_t)u) << 16);
}

#if defined(__has_builtin)
#  if __has_builtin(__builtin_amdgcn_cvt_pk_bf16_f32)
#    define HAVE_PK_BF16 1
#  endif
#endif
__device__ __forceinline__ uint_t pk_bf16(float a, float b) {
#ifdef HAVE_PK_BF16
    auto r = __builtin_amdgcn_cvt_pk_bf16_f32(a, b);
    union { decltype(r) v; uint_t u; } cv; cv.v = r;
    return cv.u;
#else
    return (uint_t)f2bf(a) | ((uint_t)f2bf(b) << 16);
#endif
}

// ---- DPP 16-lane rotation-reduction (VALU pipe; replaces ds_swizzle shuffles) ----
template<int CTRL>
__device__ __forceinline__ float row_ror_add(float v) {
    int r = __builtin_amdgcn_update_dpp(0, __float_as_int(v), CTRL, 0xF, 0xF, true);
    return v + __int_as_float(r);
}
__device__ __forceinline__ float sum16(float v) {
    v = row_ror_add<0x128>(v);   // row_ror:8
    v = row_ror_add<0x124>(v);   // row_ror:4
    v = row_ror_add<0x122>(v);   // row_ror:2
    v = row_ror_add<0x121>(v);   // row_ror:1
    return v;
}

// ---- weight prep: W[K][512] fp32 -> Wt[n][k] bf16, zero-padded to Kpad ----
__global__ __launch_bounds__(256) void prep_w(const float* __restrict__ W,
                                              ushort_t* __restrict__ dst,
                                              int K, int Kpad) {
    int n = blockIdx.x;            // 0..511
    for (int k = threadIdx.x; k < Kpad; k += 256) {
        float v = (k < K) ? W[k * 512 + n] : 0.0f;
        dst[n * Kpad + k] = f2bf(v);
    }
}

// One fused layer. L0==true: tangent GEMMs skipped — L0 tangent pre-activations
// are W0 rows 2,3 (JVP of one-hot through the concat), loaded directly.
template<int KPAD, bool L0>
__device__ __forceinline__ void do_layer(
    const ushort_t* __restrict__ Wt, const float* __restrict__ Wfull,
    const float* __restrict__ bb,
    const float* __restrict__ gg, const float* __restrict__ bev,
    ushort_t* A_s, float (*sbuf)[16][6], float (*pbuf)[8])
{
    const int tid  = threadIdx.x;
    const int w    = tid >> 6;      // wave 0..7
    const int lane = tid & 63;
    const int q    = lane >> 4;     // quad 0..3
    const int c16  = lane & 15;
    const int nb   = w * 64;        // wave's 64-column base

    constexpr int MT = L0 ? 1 : 3;  // m-tiles in the GEMM

    f32x4 acc[MT][4];
#pragma unroll
    for (int m = 0; m < MT; m++)
#pragma unroll
        for (int j = 0; j < 4; j++) acc[m][j] = (f32x4){0.f, 0.f, 0.f, 0.f};

    const int koff = q * 8;
    const ushort_t* bp = Wt + (nb + c16) * KPAD + koff;
    const ushort_t* ap = A_s + c16 * SROW + koff;

#pragma unroll
    for (int ks = 0; ks < KPAD / 32; ks++) {
        bf16x8 af[MT], bf[4];
#pragma unroll
        for (int m = 0; m < MT; m++)
            af[m] = *(const bf16x8*)(ap + m * 16 * SROW + ks * 32);
#pragma unroll
        for (int j = 0; j < 4; j++)
            bf[j] = *(const bf16x8*)(bp + j * 16 * KPAD + ks * 32);
#pragma unroll
        for (int m = 0; m < MT; m++)
#pragma unroll
            for (int j = 0; j < 4; j++)
                acc[m][j] = __builtin_amdgcn_mfma_f32_16x16x32_bf16(af[m], bf[j], acc[m][j], 0, 0, 0);
    }

    // L0: tangent pre-activations direct from W0 rows 2,3 (token-independent)
    float tu0[4], tu1[4];
    if constexpr (L0) {
#pragma unroll
        for (int j = 0; j < 4; j++) {
            tu0[j] = Wfull[2 * 512 + nb + 16 * j + c16];
            tu1[j] = Wfull[3 * 512 + nb + 16 * j + c16];
        }
    }

    // bias on primal rows
#pragma unroll
    for (int j = 0; j < 4; j++) {
        float bv = bb[nb + 16 * j + c16];
#pragma unroll
        for (int r = 0; r < 4; r++) acc[0][j][r] += bv;
    }

    // wave-local LN stats (6 sums per token over this wave's 64 cols) — DPP reduction
    float st[4][6];
#pragma unroll
    for (int r = 0; r < 4; r++) {
        float s1 = 0.f, s2 = 0.f, a0 = 0.f, x0 = 0.f, a1 = 0.f, x1 = 0.f;
#pragma unroll
        for (int j = 0; j < 4; j++) {
            float p  = acc[0][j][r];
            float u0 = L0 ? tu0[j] : acc[1 % MT][j][r];
            float u1 = L0 ? tu1[j] : acc[2 % MT][j][r];
            s1 += p; s2 += p * p;
            a0 += u0; x0 += p * u0;
            a1 += u1; x1 += p * u1;
        }
        st[r][0] = s1; st[r][1] = s2; st[r][2] = a0; st[r][3] = x0; st[r][4] = a1; st[r][5] = x1;
    }
#pragma unroll
    for (int r = 0; r < 4; r++)
#pragma unroll
        for (int s = 0; s < 6; s++) st[r][s] = sum16(st[r][s]);
    if (c16 == 0) {
#pragma unroll
        for (int r = 0; r < 4; r++)
#pragma unroll
            for (int s = 0; s < 6; s++) sbuf[w][4 * q + r][s] = st[r][s];
    }
    __syncthreads();

    // one thread per token finalizes LN params
    if (tid < TM) {
        float s[6] = {0.f, 0.f, 0.f, 0.f, 0.f, 0.f};
#pragma unroll
        for (int ww = 0; ww < 8; ww++)
#pragma unroll
            for (int k = 0; k < 6; k++) s[k] += sbuf[ww][tid][k];
        const float inv = 1.0f / 512.0f;
        float mu  = s[0] * inv;
        float var = s[1] * inv - mu * mu;
        float rs  = rsqrtf(var + EPS);
        float dm0 = s[2] * inv, dm1 = s[4] * inv;
        float c0 = rs * (s[3] * inv - mu * dm0);
        float c1 = rs * (s[5] * inv - mu * dm1);
        pbuf[tid][0] = mu; pbuf[tid][1] = rs;
        pbuf[tid][2] = dm0; pbuf[tid][3] = c0;
        pbuf[tid][4] = dm1; pbuf[tid][5] = c1;
    }
    __syncthreads();

    // epilogue: softplus(LN) + JVP (R18-identical math), packed bf16 conversion,
    // same 12 b16 stores per r at the same addresses/order as R18
    float gv[4], bvv[4];
#pragma unroll
    for (int j = 0; j < 4; j++) {
        gv[j]  = gg[nb + 16 * j + c16];
        bvv[j] = bev[nb + 16 * j + c16];
    }
#pragma unroll
    for (int r = 0; r < 4; r++) {
        int tok = 4 * q + r;
        float4 pa = *(const float4*)&pbuf[tok][0];
        float4 pb = *(const float4*)&pbuf[tok][4];
        float mu = pa.x, rs = pa.y, dm0 = pa.z, c0 = pa.w;
        float dm1 = pb.x, c1 = pb.y;
        float spv[4], d0v[4], d1v[4];
#pragma unroll
        for (int j = 0; j < 4; j++) {
            float p  = acc[0][j][r];
            float u0 = L0 ? tu0[j] : acc[1 % MT][j][r];
            float u1 = L0 ? tu1[j] : acc[2 % MT][j][r];
            float xh = (p - mu) * rs;
            float y  = fmaf(xh, gv[j], bvv[j]);
            float e  = __expf(-fabsf(y));
            float rinv = 1.0f / (1.0f + e);
            float sig  = (y >= 0.f) ? rinv : e * rinv;
            float sp   = fmaxf(y, 0.f) + __logf(1.0f + e);
            float grs  = gv[j] * rs;
            float dy0  = grs * (u0 - dm0 - xh * c0);
            float dy1  = grs * (u1 - dm1 - xh * c1);
            spv[j] = sp;
            d0v[j] = sig * dy0;
            d1v[j] = sig * dy1;
        }
        uint_t ps01 = pk_bf16(spv[0], spv[1]), ps23 = pk_bf16(spv[2], spv[3]);
        uint_t p001 = pk_bf16(d0v[0], d0v[1]), p023 = pk_bf16(d0v[2], d0v[3]);
        uint_t p101 = pk_bf16(d1v[0], d1v[1]), p123 = pk_bf16(d1v[2], d1v[3]);
        int n0 = nb + c16;
        ushort_t* xr  = A_s + tok * SROW + 2 + n0;
        ushort_t* u0r = xr + 16 * SROW;
        ushort_t* u1r = xr + 32 * SROW;
        xr[0]  = (ushort_t)ps01;  xr[16]  = (ushort_t)(ps01 >> 16);
        xr[32] = (ushort_t)ps23;  xr[48]  = (ushort_t)(ps23 >> 16);
        u0r[0] = (ushort_t)p001;  u0r[16] = (ushort_t)(p001 >> 16);
        u0r[32] = (ushort_t)p023; u0r[48] = (ushort_t)(p023 >> 16);
        u1r[0] = (ushort_t)p101;  u1r[16] = (ushort_t)(p101 >> 16);
        u1r[32] = (ushort_t)p123; u1r[48] = (ushort_t)(p123 >> 16);
    }
    __syncthreads();
}

__global__ __launch_bounds__(512, 4) void ode_mfma(
    const float* __restrict__ t, const float* __restrict__ z, const float* __restrict__ cond,
    const ushort_t* __restrict__ Wt0, const ushort_t* __restrict__ Wt1, const ushort_t* __restrict__ Wt2,
    const float* __restrict__ W0full,
    const float* __restrict__ b0, const float* __restrict__ g0, const float* __restrict__ be0,
    const float* __restrict__ b1, const float* __restrict__ g1, const float* __restrict__ be1,
    const float* __restrict__ b2, const float* __restrict__ g2, const float* __restrict__ be2,
    const float* __restrict__ W3, const float* __restrict__ b3,
    float* __restrict__ out)
{
    __shared__ ushort_t A_s[48 * SROW];       // rows 0..15 primal x, 16..31 u0, 32..47 u1
    __shared__ float sbuf[8][16][6];
    __shared__ float pbuf[16][8];

    const int tid = threadIdx.x;

    // ---------------- init A (R18-identical: full zero, two barriers) ----------------
    {   uint_t* A32 = (uint_t*)A_s;
        for (int i = tid; i < 48 * SROW / 2; i += 512) A32[i] = 0u;
    }
    __syncthreads();
    const float te = t[0];
    if (tid < TM) {
        int tok = tid;
        int gm  = blockIdx.x * TM + tok;
        int si  = gm & 63;
        float pos = (float)(si + 1) * (1.0f / 64.0f);
        A_s[tok * SROW + 0] = f2bf(te);
        A_s[tok * SROW + 1] = f2bf(pos);
        A_s[tok * SROW + 2] = f2bf(z[gm * 2 + 0]);
        A_s[tok * SROW + 3] = f2bf(z[gm * 2 + 1]);
        // L0 tangent GEMM is skipped; tangent rows' k in [2,514) written by L0 epilogue.
    }
    {   // all 16 tokens of a block share one batch row (16 | 64)
        int bi = (blockIdx.x * TM) >> 6;
        for (int i = tid; i < TM * 128; i += 512) {
            int tok = i >> 7, c = i & 127;
            A_s[tok * SROW + 4 + c] = f2bf(cond[bi * 128 + c]);
        }
    }
    __syncthreads();

    do_layer<K0P, true >(Wt0, W0full, b0, g0, be0, A_s, sbuf, pbuf);
    do_layer<KHP, false>(Wt1, nullptr, b1, g1, be1, A_s, sbuf, pbuf);
    do_layer<KHP, false>(Wt2, nullptr, b2, g2, be2, A_s, sbuf, pbuf);

    // ---------------- layer 3: Kin=514 -> 2 outputs + divergence ----------------
    {
        int tok = tid >> 5;       // 0..15
        int l32 = tid & 31;
        int gm  = blockIdx.x * TM + tok;
        const float2* W3v = (const float2*)W3;
        float a0 = 0.f, a1 = 0.f, d0 = 0.f, d1 = 0.f;
        for (int k = l32; k < 514; k += 32) {
            float2 wv = W3v[k];
            float ax  = bf2f(A_s[tok * SROW + k]);
            float au0 = bf2f(A_s[(16 + tok) * SROW + k]);
            float au1 = bf2f(A_s[(32 + tok) * SROW + k]);
            a0 = fmaf(ax, wv.x, a0);
            a1 = fmaf(ax, wv.y, a1);
            d0 = fmaf(au0, wv.x, d0);
            d1 = fmaf(au1, wv.y, d1);
        }
#pragma unroll
        for (int d = 1; d <= 16; d <<= 1) {
            a0 += __shfl_xor(a0, d); a1 += __shfl_xor(a1, d);
            d0 += __shfl_xor(d0, d); d1 += __shfl_xor(d1, d);
        }
        if (l32 == 0) {
            out[gm * 2 + 0]    = a0 + b3[0];
            out[gm * 2 + 1]    = a1 + b3[1];
            out[NTOK * 2 + gm] = -(d0 + d1);
        }
    }
}

extern "C" void kernel_launch(void* const* d_in, const int* in_sizes, int n_in,
                              void* d_out, int out_size, void* d_ws, size_t ws_size,
                              hipStream_t stream) {
    const float* t    = (const float*)d_in[0];
    const float* z    = (const float*)d_in[1];
    const float* cond = (const float*)d_in[2];
    const float* W0   = (const float*)d_in[3];
    const float* b0   = (const float*)d_in[4];
    const float* g0   = (const float*)d_in[5];
    const float* be0  = (const float*)d_in[6];
    const float* W1   = (const float*)d_in[7];
    const float* b1   = (const float*)d_in[8];
    const float* g1   = (const float*)d_in[9];
    const float* be1  = (const float*)d_in[10];
    const float* W2   = (const float*)d_in[11];
    const float* b2   = (const float*)d_in[12];
    const float* g2   = (const float*)d_in[13];
    const float* be2  = (const float*)d_in[14];
    const float* W3   = (const float*)d_in[15];
    const float* b3   = (const float*)d_in[16];
    float* out = (float*)d_out;

    ushort_t* Wt0 = (ushort_t*)d_ws;                    // 512*160
    ushort_t* Wt1 = Wt0 + 512 * K0P;                    // 512*544
    ushort_t* Wt2 = Wt1 + 512 * KHP;                    // 512*544

    hipLaunchKernelGGL(prep_w, dim3(512), dim3(256), 0, stream, W0, Wt0, 132, K0P);
    hipLaunchKernelGGL(prep_w, dim3(512), dim3(256), 0, stream, W1, Wt1, 514, KHP);
    hipLaunchKernelGGL(prep_w, dim3(512), dim3(256), 0, stream, W2, Wt2, 514, KHP);

    hipLaunchKernelGGL(ode_mfma, dim3(NTOK / TM), dim3(512), 0, stream,
                       t, z, cond, Wt0, Wt1, Wt2, W0,
                       b0, g0, be0, b1, g1, be1, b2, g2, be2, W3, b3, out);
}